// Round 1
// baseline (4129.503 us; speedup 1.0000x reference)
//
#include <hip/hip_runtime.h>
#include <math.h>

// ---------------------------------------------------------------------------
// NormDist (Lp, p=8) IBP AlexNet forward.
// Identity: lp8(d) = (sum d^8)^(1/8)  -- no max-normalization needed in fp32
// (max intermediate ~3e2 -> d^8 ~ 8e19 << 3.4e38). s^(1/8) = 3x sqrtf.
// ReLU after normdist layers is a no-op (norms >= 0); only FC layers need it.
// Zero-padding applies to c/lo/hi alike (patches extracted after pad).
// ---------------------------------------------------------------------------

template<int K>
__global__ void normdist_conv_kernel(
    const float* __restrict__ IC, const float* __restrict__ IL, const float* __restrict__ IU,
    const float* __restrict__ W,
    float* __restrict__ OC, float* __restrict__ OL, float* __restrict__ OU,
    int B, int Cin, int Hin, int Win, int O, int S, int P, int Ho, int Wo)
{
    int idx = blockIdx.x * blockDim.x + threadIdx.x;
    int total = B * O * Ho * Wo;
    if (idx >= total) return;
    int ow = idx % Wo; int t = idx / Wo;
    int oh = t % Ho;   t /= Ho;
    int o  = t % O;    int b = t / O;

    const float* wbase = W + (size_t)o * Cin * K * K;
    int ih0 = oh * S - P, iw0 = ow * S - P;
    size_t plane = (size_t)Hin * Win;
    const float* cb = IC + (size_t)b * Cin * plane;
    const float* lb = IL + (size_t)b * Cin * plane;
    const float* ub = IU + (size_t)b * Cin * plane;

    float sc = 0.f, sl = 0.f, sh = 0.f;
    for (int c = 0; c < Cin; ++c) {
        const float* wc = wbase + c * K * K;
        #pragma unroll
        for (int ki = 0; ki < K; ++ki) {
            int ih = ih0 + ki;
            bool rowok = (unsigned)ih < (unsigned)Hin;
            #pragma unroll
            for (int kj = 0; kj < K; ++kj) {
                int iw = iw0 + kj;
                bool ok = rowok && ((unsigned)iw < (unsigned)Win);
                float pc = 0.f, pl = 0.f, ph = 0.f;
                if (ok) {
                    int off = ih * Win + iw;
                    pc = cb[off]; pl = lb[off]; ph = ub[off];
                }
                float w = wc[ki * K + kj];
                // center: |pc-w|^8 == (pc-w)^8, abs free
                float a = pc - w;
                float a2 = a * a, a4 = a2 * a2;
                sc = fmaf(a4, a4, sc);
                // lower: max(pl-w, w-ph, 0)^8
                float x = pl - w, y = ph - w;
                float dl = fmaxf(fmaxf(x, -y), 0.f);
                float e2 = dl * dl, e4 = e2 * e2;
                sl = fmaf(e4, e4, sl);
                // upper: max(|pl-w|,|ph-w|)^8 -> max(x^2,y^2)^4
                float h2 = fmaxf(x * x, y * y);
                float h4 = h2 * h2;
                sh = fmaf(h4, h4, sh);
            }
        }
        cb += plane; lb += plane; ub += plane;
    }
    OC[idx] = sqrtf(sqrtf(sqrtf(sc)));
    OL[idx] = sqrtf(sqrtf(sqrtf(sl)));
    OU[idx] = sqrtf(sqrtf(sqrtf(sh)));
}

// 3x3 stride-2 VALID maxpool over the three bound tensors (stored back-to-back)
__global__ void maxpool_kernel(const float* __restrict__ in, float* __restrict__ out,
                               int BC, int Hin, int Win, int Ho, int Wo,
                               int n_in, int n_out)
{
    int idx = blockIdx.x * blockDim.x + threadIdx.x;
    int per = BC * Ho * Wo;
    int total = 3 * per;
    if (idx >= total) return;
    int tsel = idx / per; int r = idx - tsel * per;
    int ow = r % Wo; int t2 = r / Wo;
    int oh = t2 % Ho; int bc = t2 / Ho;
    const float* ip = in + (size_t)tsel * n_in + (size_t)bc * Hin * Win;
    int ih0 = oh * 2, iw0 = ow * 2;
    float m = -INFINITY;
    #pragma unroll
    for (int i = 0; i < 3; ++i)
        #pragma unroll
        for (int j = 0; j < 3; ++j)
            m = fmaxf(m, ip[(ih0 + i) * Win + (iw0 + j)]);
    out[(size_t)tsel * n_out + r] = m;
}

// bound_linear: oc = c@W.T ; mid = ((l+u)/2)@W.T ; rad = ((u-l)/2)@|W|.T
// mode bit0: relu; bit1: final negate (writes -c, -lo, -hi to OC/OL/OU)
__global__ void bound_linear_kernel(
    const float* __restrict__ IC, const float* __restrict__ IL, const float* __restrict__ IU,
    const float* __restrict__ W, const float* __restrict__ bias,
    float* __restrict__ OC, float* __restrict__ OL, float* __restrict__ OU,
    int B, int In, int Out, int mode)
{
    int idx = blockIdx.x * blockDim.x + threadIdx.x;
    if (idx >= B * Out) return;
    int o = idx % Out, b = idx / Out;
    const float* wr = W  + (size_t)o * In;
    const float* cr = IC + (size_t)b * In;
    const float* lr = IL + (size_t)b * In;
    const float* ur = IU + (size_t)b * In;
    float sc = 0.f, sm = 0.f, sr = 0.f;
    for (int i = 0; i < In; ++i) {
        float w = wr[i];
        float c = cr[i], l = lr[i], u = ur[i];
        sc = fmaf(c, w, sc);
        sm = fmaf((l + u) * 0.5f, w, sm);
        sr = fmaf((u - l) * 0.5f, fabsf(w), sr);
    }
    if (bias) { float bb = bias[o]; sc += bb; sm += bb; }
    float lo = sm - sr, hi = sm + sr;
    if (mode & 1) { sc = fmaxf(sc, 0.f); lo = fmaxf(lo, 0.f); hi = fmaxf(hi, 0.f); }
    if (mode & 2) { OC[idx] = -sc; OL[idx] = -lo; OU[idx] = -hi; }
    else          { OC[idx] =  sc; OL[idx] =  lo; OU[idx] =  hi; }
}

extern "C" void kernel_launch(void* const* d_in, const int* in_sizes, int n_in,
                              void* d_out, int out_size, void* d_ws, size_t ws_size,
                              hipStream_t stream)
{
    const float* x   = (const float*)d_in[0];
    const float* lo  = (const float*)d_in[1];
    const float* hi  = (const float*)d_in[2];
    const float* w1  = (const float*)d_in[3];
    const float* w2  = (const float*)d_in[4];
    const float* w3  = (const float*)d_in[5];
    const float* w4  = (const float*)d_in[6];
    const float* w5  = (const float*)d_in[7];
    const float* fw1 = (const float*)d_in[8];
    const float* fw2 = (const float*)d_in[9];
    const float* fw3 = (const float*)d_in[10];
    const float* fb3 = (const float*)d_in[11];
    float* out = (float*)d_out;
    float* ws  = (float*)d_ws;

    const size_t n_c1 = 16u * 96 * 15 * 15;   // 345600
    const size_t n_p1 = 16u * 96 * 7 * 7;     // 75264
    const size_t n_c2 = 16u * 256 * 7 * 7;    // 200704
    const size_t n_p2 = 16u * 256 * 3 * 3;    // 36864
    const size_t n_c3 = 16u * 384 * 3 * 3;    // 55296
    const size_t n_c4 = n_c3;
    const size_t n_c5 = 16u * 256 * 3 * 3;    // 36864
    const size_t n_f1 = 16u * 1024;
    const size_t n_f2 = 16u * 512;

    float* A  = ws;                // conv1 out
    float* Bp = A  + 3 * n_c1;     // pool1 out
    float* Cc = Bp + 3 * n_p1;     // conv2 out
    float* D  = Cc + 3 * n_c2;     // pool2 out
    float* E  = D  + 3 * n_p2;     // conv3 out
    float* F  = E  + 3 * n_c3;     // conv4 out
    float* G  = F  + 3 * n_c4;     // conv5 out
    float* H  = G  + 3 * n_c5;     // fc1 out
    float* I  = H  + 3 * n_f1;     // fc2 out

    const int BS = 256;

    // conv1: [16,3,32,32] k7 s2 p2 -> [16,96,15,15]
    {
        int tot = (int)n_c1;
        normdist_conv_kernel<7><<<(tot + BS - 1) / BS, BS, 0, stream>>>(
            x, lo, hi, w1, A, A + n_c1, A + 2 * n_c1,
            16, 3, 32, 32, 96, 2, 2, 15, 15);
    }
    // pool1: 15 -> 7
    {
        int tot = 3 * (int)n_p1;
        maxpool_kernel<<<(tot + BS - 1) / BS, BS, 0, stream>>>(
            A, Bp, 16 * 96, 15, 15, 7, 7, (int)n_c1, (int)n_p1);
    }
    // conv2: [16,96,7,7] k5 s1 p2 -> [16,256,7,7]
    {
        int tot = (int)n_c2;
        normdist_conv_kernel<5><<<(tot + BS - 1) / BS, BS, 0, stream>>>(
            Bp, Bp + n_p1, Bp + 2 * n_p1, w2, Cc, Cc + n_c2, Cc + 2 * n_c2,
            16, 96, 7, 7, 256, 1, 2, 7, 7);
    }
    // pool2: 7 -> 3
    {
        int tot = 3 * (int)n_p2;
        maxpool_kernel<<<(tot + BS - 1) / BS, BS, 0, stream>>>(
            Cc, D, 16 * 256, 7, 7, 3, 3, (int)n_c2, (int)n_p2);
    }
    // conv3: [16,256,3,3] k3 s1 p1 -> [16,384,3,3]
    {
        int tot = (int)n_c3;
        normdist_conv_kernel<3><<<(tot + BS - 1) / BS, BS, 0, stream>>>(
            D, D + n_p2, D + 2 * n_p2, w3, E, E + n_c3, E + 2 * n_c3,
            16, 256, 3, 3, 384, 1, 1, 3, 3);
    }
    // conv4: [16,384,3,3] -> [16,384,3,3]
    {
        int tot = (int)n_c4;
        normdist_conv_kernel<3><<<(tot + BS - 1) / BS, BS, 0, stream>>>(
            E, E + n_c3, E + 2 * n_c3, w4, F, F + n_c4, F + 2 * n_c4,
            16, 384, 3, 3, 384, 1, 1, 3, 3);
    }
    // conv5: [16,384,3,3] -> [16,256,3,3]
    {
        int tot = (int)n_c5;
        normdist_conv_kernel<3><<<(tot + BS - 1) / BS, BS, 0, stream>>>(
            F, F + n_c4, F + 2 * n_c4, w5, G, G + n_c5, G + 2 * n_c5,
            16, 384, 3, 3, 256, 1, 1, 3, 3);
    }
    // fc1: 2304 -> 1024, relu
    {
        int tot = 16 * 1024;
        bound_linear_kernel<<<(tot + BS - 1) / BS, BS, 0, stream>>>(
            G, G + n_c5, G + 2 * n_c5, fw1, nullptr,
            H, H + n_f1, H + 2 * n_f1, 16, 2304, 1024, 1);
    }
    // fc2: 1024 -> 512, relu
    {
        int tot = 16 * 512;
        bound_linear_kernel<<<(tot + BS - 1) / BS, BS, 0, stream>>>(
            H, H + n_f1, H + 2 * n_f1, fw2, nullptr,
            I, I + n_f2, I + 2 * n_f2, 16, 1024, 512, 1);
    }
    // fc3: 512 -> 10, +bias, final negate+swap: out = [-c | -u | -l]
    {
        int tot = 16 * 10;
        bound_linear_kernel<<<(tot + BS - 1) / BS, BS, 0, stream>>>(
            I, I + n_f2, I + 2 * n_f2, fw3, fb3,
            out /* -c */, out + 320 /* -l */, out + 160 /* -u */,
            16, 512, 10, 2);
    }
}

// Round 2
// 3182.918 us; speedup vs baseline: 1.2974x; 1.2974x over previous
//
#include <hip/hip_runtime.h>
#include <math.h>

// ---------------------------------------------------------------------------
// NormDist (Lp, p=8) IBP AlexNet forward. Round 2: register row-tiling +
// channel-split additive d^8 partials.
//   lp8(d) = (sum d^8)^(1/8); sum is additive across channel chunks.
//   ReLU after conv layers is a no-op (norms >= 0).
//   Zero-padding: OOB taps contribute w^8 to all three sums (handled by
//   loading 0 for OOB positions).
// ---------------------------------------------------------------------------

__device__ __forceinline__ float rt8(float s) { return sqrtf(sqrtf(sqrtf(s))); }

// Thread computes TILE consecutive outputs along W for one (chunk,b,o,oh,tile).
// If ROOT: writes final ^(1/8) values to OUT (3 tensors of N at OUT,+N,+2N).
// Else: writes raw partial sums to OUT + chunk*3*N.
template<int K, int S, int TILE, bool ROOT>
__global__ void nd_conv(
    const float* __restrict__ IC, const float* __restrict__ IL, const float* __restrict__ IU,
    const float* __restrict__ W, float* __restrict__ OUT,
    int B, int Cin, int CC, int NCH, int Hin, int Win, int O, int PAD,
    int Ho, int Wo, int NT)
{
    constexpr int RL = (TILE - 1) * S + K;  // padded row length in registers
    int idx = blockIdx.x * blockDim.x + threadIdx.x;
    int total = NCH * B * O * Ho * NT;
    if (idx >= total) return;
    int tile = idx % NT; int t = idx / NT;
    int oh = t % Ho;  t /= Ho;
    int o  = t % O;   t /= O;
    int b  = t % B;   int chunk = t / B;
    int c0 = chunk * CC;

    size_t plane = (size_t)Hin * Win;
    const float* cb = IC + ((size_t)b * Cin + c0) * plane;
    const float* lb = IL + ((size_t)b * Cin + c0) * plane;
    const float* ub = IU + ((size_t)b * Cin + c0) * plane;
    const float* wb = W + ((size_t)o * Cin + c0) * (K * K);

    float accC[TILE], accL[TILE], accH[TILE];
    #pragma unroll
    for (int u = 0; u < TILE; ++u) { accC[u] = 0.f; accL[u] = 0.f; accH[u] = 0.f; }

    int ow0 = tile * TILE;
    int iw0 = ow0 * S - PAD;

    for (int c = 0; c < CC; ++c) {
        const float* cp = cb + (size_t)c * plane;
        const float* lp = lb + (size_t)c * plane;
        const float* up = ub + (size_t)c * plane;
        const float* wc = wb + c * K * K;
        #pragma unroll
        for (int ki = 0; ki < K; ++ki) {
            int ih = oh * S - PAD + ki;
            bool rowok = (unsigned)ih < (unsigned)Hin;
            int rowoff = ih * Win;
            float rc[RL], rl[RL], rh[RL];
            #pragma unroll
            for (int r = 0; r < RL; ++r) {
                int iw = iw0 + r;
                bool ok = rowok && ((unsigned)iw < (unsigned)Win);
                int off = rowoff + iw;
                rc[r] = ok ? cp[off] : 0.f;
                rl[r] = ok ? lp[off] : 0.f;
                rh[r] = ok ? up[off] : 0.f;
            }
            const float* wp = wc + ki * K;
            #pragma unroll
            for (int kj = 0; kj < K; ++kj) {
                float w = wp[kj];
                #pragma unroll
                for (int u = 0; u < TILE; ++u) {
                    int r = u * S + kj;
                    float a = rc[r] - w;
                    float a2 = a * a, a4 = a2 * a2;
                    accC[u] = fmaf(a4, a4, accC[u]);
                    float x = rl[r] - w, y = rh[r] - w;
                    float dl = fmaxf(fmaxf(x, -y), 0.f);
                    float e2 = dl * dl, e4 = e2 * e2;
                    accL[u] = fmaf(e4, e4, accL[u]);
                    float h2 = fmaxf(x * x, y * y);
                    float h4 = h2 * h2;
                    accH[u] = fmaf(h4, h4, accH[u]);
                }
            }
        }
    }

    size_t N = (size_t)B * O * Ho * Wo;
    size_t base = (((size_t)b * O + o) * Ho + oh) * Wo + ow0;
    if (ROOT) {
        #pragma unroll
        for (int u = 0; u < TILE; ++u) {
            OUT[base + u]         = rt8(accC[u]);
            OUT[N + base + u]     = rt8(accL[u]);
            OUT[2 * N + base + u] = rt8(accH[u]);
        }
    } else {
        float* p = OUT + (size_t)chunk * 3 * N;
        #pragma unroll
        for (int u = 0; u < TILE; ++u) {
            p[base + u]         = accC[u];
            p[N + base + u]     = accL[u];
            p[2 * N + base + u] = accH[u];
        }
    }
}

// Sum NCH partial d^8 blocks and apply ^(1/8). threads over 3N.
__global__ void conv_combine(const float* __restrict__ P, float* __restrict__ OUT,
                             size_t N, int NCH)
{
    size_t idx = (size_t)blockIdx.x * blockDim.x + threadIdx.x;
    if (idx >= 3 * N) return;
    float s = 0.f;
    for (int ch = 0; ch < NCH; ++ch) s += P[(size_t)ch * 3 * N + idx];
    OUT[idx] = rt8(s);
}

// 3x3 stride-2 VALID maxpool over the three bound tensors (back-to-back)
__global__ void maxpool_kernel(const float* __restrict__ in, float* __restrict__ out,
                               int BC, int Hin, int Win, int Ho, int Wo,
                               int n_in, int n_out)
{
    int idx = blockIdx.x * blockDim.x + threadIdx.x;
    int per = BC * Ho * Wo;
    if (idx >= 3 * per) return;
    int tsel = idx / per; int r = idx - tsel * per;
    int ow = r % Wo; int t2 = r / Wo;
    int oh = t2 % Ho; int bc = t2 / Ho;
    const float* ip = in + (size_t)tsel * n_in + (size_t)bc * Hin * Win;
    int ih0 = oh * 2, iw0 = ow * 2;
    float m = -INFINITY;
    #pragma unroll
    for (int i = 0; i < 3; ++i)
        #pragma unroll
        for (int j = 0; j < 3; ++j)
            m = fmaxf(m, ip[(ih0 + i) * Win + (iw0 + j)]);
    out[(size_t)tsel * n_out + r] = m;
}

// FC partial: thread per (chunk,b,o), float4 loads over its In-chunk.
// Writes sc/sm/sr partials to P + chunk*3*N (+0N/+1N/+2N).
__global__ void fc_partial(
    const float* __restrict__ IC, const float* __restrict__ IL, const float* __restrict__ IU,
    const float* __restrict__ W, float* __restrict__ P,
    int B, int In, int Out, int CC, int NCH)
{
    int idx = blockIdx.x * blockDim.x + threadIdx.x;
    if (idx >= NCH * B * Out) return;
    int o = idx % Out; int t = idx / Out;
    int b = t % B; int chunk = t / B;
    int i0 = chunk * CC;
    const float4* wr = (const float4*)(W  + (size_t)o * In + i0);
    const float4* cr = (const float4*)(IC + (size_t)b * In + i0);
    const float4* lr = (const float4*)(IL + (size_t)b * In + i0);
    const float4* ur = (const float4*)(IU + (size_t)b * In + i0);
    float sc = 0.f, sm = 0.f, sr = 0.f;
    for (int i = 0; i < CC / 4; ++i) {
        float4 w4 = wr[i], c4 = cr[i], l4 = lr[i], u4 = ur[i];
        sc = fmaf(c4.x, w4.x, sc); sc = fmaf(c4.y, w4.y, sc);
        sc = fmaf(c4.z, w4.z, sc); sc = fmaf(c4.w, w4.w, sc);
        sm = fmaf((l4.x + u4.x) * 0.5f, w4.x, sm);
        sm = fmaf((l4.y + u4.y) * 0.5f, w4.y, sm);
        sm = fmaf((l4.z + u4.z) * 0.5f, w4.z, sm);
        sm = fmaf((l4.w + u4.w) * 0.5f, w4.w, sm);
        sr = fmaf((u4.x - l4.x) * 0.5f, fabsf(w4.x), sr);
        sr = fmaf((u4.y - l4.y) * 0.5f, fabsf(w4.y), sr);
        sr = fmaf((u4.z - l4.z) * 0.5f, fabsf(w4.z), sr);
        sr = fmaf((u4.w - l4.w) * 0.5f, fabsf(w4.w), sr);
    }
    size_t N = (size_t)B * Out;
    size_t base = (size_t)b * Out + o;
    float* p = P + (size_t)chunk * 3 * N;
    p[base] = sc; p[N + base] = sm; p[2 * N + base] = sr;
}

// Combine fc partials, apply relu. Writes c/lo/hi tensors at OUT,+N,+2N.
__global__ void fc_combine(const float* __restrict__ P, float* __restrict__ OUT,
                           size_t N, int NCH)
{
    size_t idx = (size_t)blockIdx.x * blockDim.x + threadIdx.x;
    if (idx >= N) return;
    float sc = 0.f, sm = 0.f, sr = 0.f;
    for (int ch = 0; ch < NCH; ++ch) {
        const float* p = P + (size_t)ch * 3 * N;
        sc += p[idx]; sm += p[N + idx]; sr += p[2 * N + idx];
    }
    OUT[idx]         = fmaxf(sc, 0.f);
    OUT[N + idx]     = fmaxf(sm - sr, 0.f);
    OUT[2 * N + idx] = fmaxf(sm + sr, 0.f);
}

// Final FC: scalar, tiny. mode bit1 = negate outputs.
__global__ void bound_linear_kernel(
    const float* __restrict__ IC, const float* __restrict__ IL, const float* __restrict__ IU,
    const float* __restrict__ W, const float* __restrict__ bias,
    float* __restrict__ OC, float* __restrict__ OL, float* __restrict__ OU,
    int B, int In, int Out)
{
    int idx = blockIdx.x * blockDim.x + threadIdx.x;
    if (idx >= B * Out) return;
    int o = idx % Out, b = idx / Out;
    const float* wr = W  + (size_t)o * In;
    const float* cr = IC + (size_t)b * In;
    const float* lr = IL + (size_t)b * In;
    const float* ur = IU + (size_t)b * In;
    float sc = 0.f, sm = 0.f, sr = 0.f;
    for (int i = 0; i < In; ++i) {
        float w = wr[i];
        sc = fmaf(cr[i], w, sc);
        sm = fmaf((lr[i] + ur[i]) * 0.5f, w, sm);
        sr = fmaf((ur[i] - lr[i]) * 0.5f, fabsf(w), sr);
    }
    float bb = bias[o]; sc += bb; sm += bb;
    OC[idx] = -sc; OL[idx] = -(sm - sr); OU[idx] = -(sm + sr);
}

extern "C" void kernel_launch(void* const* d_in, const int* in_sizes, int n_in,
                              void* d_out, int out_size, void* d_ws, size_t ws_size,
                              hipStream_t stream)
{
    const float* x   = (const float*)d_in[0];
    const float* lo  = (const float*)d_in[1];
    const float* hi  = (const float*)d_in[2];
    const float* w1  = (const float*)d_in[3];
    const float* w2  = (const float*)d_in[4];
    const float* w3  = (const float*)d_in[5];
    const float* w4  = (const float*)d_in[6];
    const float* w5  = (const float*)d_in[7];
    const float* fw1 = (const float*)d_in[8];
    const float* fw2 = (const float*)d_in[9];
    const float* fw3 = (const float*)d_in[10];
    const float* fb3 = (const float*)d_in[11];
    float* out = (float*)d_out;
    float* ws  = (float*)d_ws;

    const size_t n_c1 = 16u * 96 * 15 * 15;   // 345600
    const size_t n_p1 = 16u * 96 * 7 * 7;     // 75264
    const size_t n_c2 = 16u * 256 * 7 * 7;    // 200704
    const size_t n_p2 = 16u * 256 * 3 * 3;    // 36864
    const size_t n_c3 = 16u * 384 * 3 * 3;    // 55296
    const size_t n_c4 = n_c3;
    const size_t n_c5 = 16u * 256 * 3 * 3;    // 36864
    const size_t n_f1 = 16u * 1024;
    const size_t n_f2 = 16u * 512;

    float* A  = ws;                // conv1 out
    float* Bp = A  + 3 * n_c1;     // pool1 out
    float* Cc = Bp + 3 * n_p1;     // conv2 out
    float* D  = Cc + 3 * n_c2;     // pool2 out
    float* E  = D  + 3 * n_p2;     // conv3 out
    float* F  = E  + 3 * n_c3;     // conv4 out
    float* G  = F  + 3 * n_c4;     // conv5 out
    float* H  = G  + 3 * n_c5;     // fc1 out
    float* I  = H  + 3 * n_f1;     // fc2 out
    float* SP = I  + 3 * n_f2;     // shared partial scratch (max 4*3*n_c2 floats)

    const int BS = 256;
    auto grid = [](size_t tot) { return dim3((unsigned)((tot + 255) / 256)); };

    // conv1: [16,3,32,32] k7 s2 p2 -> [16,96,15,15]; TILE=5, NT=3, no split
    {
        size_t tot = 1u * 16 * 96 * 15 * 3;
        nd_conv<7, 2, 5, true><<<grid(tot), BS, 0, stream>>>(
            x, lo, hi, w1, A, 16, 3, 3, 1, 32, 32, 96, 2, 15, 15, 3);
    }
    // pool1: 15 -> 7
    maxpool_kernel<<<grid(3 * n_p1), BS, 0, stream>>>(
        A, Bp, 16 * 96, 15, 15, 7, 7, (int)n_c1, (int)n_p1);
    // conv2: [16,96,7,7] k5 s1 p2 -> [16,256,7,7]; TILE=7, split 4x24
    {
        size_t tot = 4u * 16 * 256 * 7 * 1;
        nd_conv<5, 1, 7, false><<<grid(tot), BS, 0, stream>>>(
            Bp, Bp + n_p1, Bp + 2 * n_p1, w2, SP, 16, 96, 24, 4, 7, 7, 256, 2, 7, 7, 1);
        conv_combine<<<grid(3 * n_c2), BS, 0, stream>>>(SP, Cc, n_c2, 4);
    }
    // pool2: 7 -> 3
    maxpool_kernel<<<grid(3 * n_p2), BS, 0, stream>>>(
        Cc, D, 16 * 256, 7, 7, 3, 3, (int)n_c2, (int)n_p2);
    // conv3: [16,256,3,3] k3 s1 p1 -> [16,384,3,3]; TILE=3, split 8x32
    {
        size_t tot = 8u * 16 * 384 * 3 * 1;
        nd_conv<3, 1, 3, false><<<grid(tot), BS, 0, stream>>>(
            D, D + n_p2, D + 2 * n_p2, w3, SP, 16, 256, 32, 8, 3, 3, 384, 1, 3, 3, 1);
        conv_combine<<<grid(3 * n_c3), BS, 0, stream>>>(SP, E, n_c3, 8);
    }
    // conv4: [16,384,3,3] -> [16,384,3,3]; split 8x48
    {
        size_t tot = 8u * 16 * 384 * 3 * 1;
        nd_conv<3, 1, 3, false><<<grid(tot), BS, 0, stream>>>(
            E, E + n_c3, E + 2 * n_c3, w4, SP, 16, 384, 48, 8, 3, 3, 384, 1, 3, 3, 1);
        conv_combine<<<grid(3 * n_c4), BS, 0, stream>>>(SP, F, n_c4, 8);
    }
    // conv5: [16,384,3,3] -> [16,256,3,3]; split 8x48
    {
        size_t tot = 8u * 16 * 256 * 3 * 1;
        nd_conv<3, 1, 3, false><<<grid(tot), BS, 0, stream>>>(
            F, F + n_c4, F + 2 * n_c4, w5, SP, 16, 384, 48, 8, 3, 3, 256, 1, 3, 3, 1);
        conv_combine<<<grid(3 * n_c5), BS, 0, stream>>>(SP, G, n_c5, 8);
    }
    // fc1: 2304 -> 1024, relu; split 8x288
    {
        size_t tot = 8u * 16 * 1024;
        fc_partial<<<grid(tot), BS, 0, stream>>>(
            G, G + n_c5, G + 2 * n_c5, fw1, SP, 16, 2304, 1024, 288, 8);
        fc_combine<<<grid(n_f1), BS, 0, stream>>>(SP, H, n_f1, 8);
    }
    // fc2: 1024 -> 512, relu; split 8x128
    {
        size_t tot = 8u * 16 * 512;
        fc_partial<<<grid(tot), BS, 0, stream>>>(
            H, H + n_f1, H + 2 * n_f1, fw2, SP, 16, 1024, 512, 128, 8);
        fc_combine<<<grid(n_f2), BS, 0, stream>>>(SP, I, n_f2, 8);
    }
    // fc3: 512 -> 10, +bias, negate+swap: out = [-c | -u | -l]
    bound_linear_kernel<<<grid(160), BS, 0, stream>>>(
        I, I + n_f2, I + 2 * n_f2, fw3, fb3,
        out /* -c */, out + 320 /* -l slot */, out + 160 /* -u slot */,
        16, 512, 10);
}

// Round 3
// 765.371 us; speedup vs baseline: 5.3954x; 4.1587x over previous
//
#include <hip/hip_runtime.h>
#include <math.h>

// ---------------------------------------------------------------------------
// NormDist (Lp, p=8) IBP AlexNet. Round 3: LDS-staged padded input slabs,
// wave-uniform output channel (scalar weight loads) for conv1/2, 7x9
// (o_local x pos) lane layout for the 3x3 convs, channel-split additive d^8
// partials + combine. lp8(d) = (sum d^8)^(1/8); relu after conv = no-op.
// Padding handled by zeroed LDS ring (padded-zero taps contribute |w|^8, which
// matches reference patch extraction on padded input).
// ---------------------------------------------------------------------------

__device__ __forceinline__ float rt8(float s) { return sqrtf(sqrtf(sqrtf(s))); }

__device__ __forceinline__ void tap16(float w, float pc, float pl, float pu,
                                      float& aC, float& aL, float& aH)
{
    float a = pc - w; float a2 = a * a, a4 = a2 * a2; aC = fmaf(a4, a4, aC);
    float x = pl - w, y = pu - w;
    float dl = fmaxf(fmaxf(x, -y), 0.f);
    float e2 = dl * dl, e4 = e2 * e2; aL = fmaf(e4, e4, aL);
    float h2 = fmaxf(x * x, y * y);
    float h4 = h2 * h2; aH = fmaf(h4, h4, aH);
}

// Structure A (conv1, conv2): block = 4 waves; wave = one o (SGPR), lanes =
// spatial positions (rounds of 64). Padded input slab [c][3][PP] in LDS.
template<int K, int S, int PAD, int CC, int HIN, int WIN, int HO, int WO, bool ROOT>
__launch_bounds__(256)
__global__ void conv_a(const float* __restrict__ IC, const float* __restrict__ IL,
                       const float* __restrict__ IU, const float* __restrict__ W,
                       float* __restrict__ OUT, int B, int Cin, int O, int OG)
{
    constexpr int PH = (HO - 1) * S + K;
    constexpr int PW = (WO - 1) * S + K;
    constexpr int PP = PH * PW;
    constexpr int HW = HIN * WIN;
    constexpr int NP = HO * WO;
    constexpr int ROUNDS = (NP + 63) / 64;
    __shared__ float lds[CC * 3 * PP];

    int og = blockIdx.x % OG;
    int b  = (blockIdx.x / OG) % B;
    int chunk = blockIdx.x / (OG * B);
    int c0 = chunk * CC;
    int tid = threadIdx.x;

    for (int i = tid; i < CC * 3 * PP; i += 256) lds[i] = 0.f;
    __syncthreads();
    for (int tsel = 0; tsel < 3; ++tsel) {
        const float* src = (tsel == 0 ? IC : (tsel == 1 ? IL : IU))
                         + ((size_t)b * Cin + c0) * HW;
        for (int e = tid; e < CC * HW; e += 256) {
            int c = e / HW, p = e % HW;
            int pr = p / WIN, pw_ = p % WIN;
            lds[c * 3 * PP + tsel * PP + (pr + PAD) * PW + (pw_ + PAD)] = src[e];
        }
    }
    __syncthreads();

    int wave = tid >> 6, lane = tid & 63;
    int o = __builtin_amdgcn_readfirstlane(og * 4 + wave);
    const float* wp = W + ((size_t)o * Cin + c0) * (K * K);

    for (int r = 0; r < ROUNDS; ++r) {
        int pos = r * 64 + lane;
        bool act = pos < NP;
        int pp = act ? pos : 0;
        int oh = pp / WO, ow = pp % WO;
        const float* sl = lds + (oh * S) * PW + ow * S;
        const float* wc = wp;
        float aC = 0.f, aL = 0.f, aH = 0.f;
        for (int c = 0; c < CC; ++c) {
            #pragma unroll
            for (int kh = 0; kh < K; ++kh)
                #pragma unroll
                for (int kw = 0; kw < K; ++kw) {
                    float w = wc[kh * K + kw];
                    tap16(w, sl[kh * PW + kw], sl[PP + kh * PW + kw],
                          sl[2 * PP + kh * PW + kw], aC, aL, aH);
                }
            sl += 3 * PP; wc += K * K;
        }
        if (act) {
            size_t N = (size_t)B * O * NP;
            size_t oidx = ((size_t)b * O + o) * NP + pos;
            if (ROOT) {
                OUT[oidx] = rt8(aC); OUT[N + oidx] = rt8(aL); OUT[2 * N + oidx] = rt8(aH);
            } else {
                float* P = OUT + (size_t)chunk * 3 * N;
                P[oidx] = aC; P[N + oidx] = aL; P[2 * N + oidx] = aH;
            }
        }
    }
}

// Structure B (3x3 convs on 3x3 maps, pad 1): lane = (o_local in [0,7) x pos
// in [0,9)); wave covers 7 o's; block 4 waves = 28 o's. Input slab [c][3][25]
// (padded 5x5) in LDS -> 9-address broadcast reads, conflict-free.
template<int CC>
__launch_bounds__(256)
__global__ void conv_b(const float* __restrict__ IC, const float* __restrict__ IL,
                       const float* __restrict__ IU, const float* __restrict__ W,
                       float* __restrict__ OUT, int B, int Cin, int O, int OB)
{
    __shared__ float lds[CC * 75];
    int ob = blockIdx.x % OB;
    int b  = (blockIdx.x / OB) % B;
    int chunk = blockIdx.x / (OB * B);
    int c0 = chunk * CC;
    int tid = threadIdx.x;

    for (int i = tid; i < CC * 75; i += 256) lds[i] = 0.f;
    __syncthreads();
    for (int tsel = 0; tsel < 3; ++tsel) {
        const float* src = (tsel == 0 ? IC : (tsel == 1 ? IL : IU))
                         + ((size_t)b * Cin + c0) * 9;
        for (int e = tid; e < CC * 9; e += 256) {
            int c = e / 9, p = e % 9;
            lds[c * 75 + tsel * 25 + (p / 3 + 1) * 5 + (p % 3 + 1)] = src[e];
        }
    }
    __syncthreads();

    int wave = tid >> 6, lane = tid & 63;
    int ol = lane / 9, pos = lane - ol * 9;      // lane 63 -> ol==7 invalid
    int o = ob * 28 + wave * 7 + ol;
    bool valid = (ol < 7) && (o < O);
    int oc_ = valid ? o : 0;
    int oh = pos / 3, ow = pos % 3;
    const float* sl = lds + oh * 5 + ow;
    const float* wb = W + ((size_t)oc_ * Cin + c0) * 9;
    float aC = 0.f, aL = 0.f, aH = 0.f;
    for (int c = 0; c < CC; ++c) {
        #pragma unroll
        for (int t = 0; t < 9; ++t) {
            int kh = t / 3, kw = t % 3;
            tap16(wb[t], sl[kh * 5 + kw], sl[25 + kh * 5 + kw],
                  sl[50 + kh * 5 + kw], aC, aL, aH);
        }
        sl += 75; wb += 9;
    }
    if (valid) {
        size_t N = (size_t)B * O * 9;
        size_t oidx = ((size_t)b * O + o) * 9 + pos;
        float* P = OUT + (size_t)chunk * 3 * N;
        P[oidx] = aC; P[N + oidx] = aL; P[2 * N + oidx] = aH;
    }
}

// Sum NCH partial d^8 blocks and apply ^(1/8).
__global__ void conv_combine(const float* __restrict__ P, float* __restrict__ OUT,
                             size_t N, int NCH)
{
    size_t idx = (size_t)blockIdx.x * blockDim.x + threadIdx.x;
    if (idx >= 3 * N) return;
    float s = 0.f;
    for (int ch = 0; ch < NCH; ++ch) s += P[(size_t)ch * 3 * N + idx];
    OUT[idx] = rt8(s);
}

__global__ void maxpool_kernel(const float* __restrict__ in, float* __restrict__ out,
                               int BC, int Hin, int Win, int Ho, int Wo,
                               int n_in, int n_out)
{
    int idx = blockIdx.x * blockDim.x + threadIdx.x;
    int per = BC * Ho * Wo;
    if (idx >= 3 * per) return;
    int tsel = idx / per; int r = idx - tsel * per;
    int ow = r % Wo; int t2 = r / Wo;
    int oh = t2 % Ho; int bc = t2 / Ho;
    const float* ip = in + (size_t)tsel * n_in + (size_t)bc * Hin * Win;
    int ih0 = oh * 2, iw0 = ow * 2;
    float m = -INFINITY;
    #pragma unroll
    for (int i = 0; i < 3; ++i)
        #pragma unroll
        for (int j = 0; j < 3; ++j)
            m = fmaxf(m, ip[(ih0 + i) * Win + (iw0 + j)]);
    out[(size_t)tsel * n_out + r] = m;
}

__global__ void fc_partial(
    const float* __restrict__ IC, const float* __restrict__ IL, const float* __restrict__ IU,
    const float* __restrict__ W, float* __restrict__ P,
    int B, int In, int Out, int CC, int NCH)
{
    int idx = blockIdx.x * blockDim.x + threadIdx.x;
    if (idx >= NCH * B * Out) return;
    int o = idx % Out; int t = idx / Out;
    int b = t % B; int chunk = t / B;
    int i0 = chunk * CC;
    const float4* wr = (const float4*)(W  + (size_t)o * In + i0);
    const float4* cr = (const float4*)(IC + (size_t)b * In + i0);
    const float4* lr = (const float4*)(IL + (size_t)b * In + i0);
    const float4* ur = (const float4*)(IU + (size_t)b * In + i0);
    float sc = 0.f, sm = 0.f, sr = 0.f;
    for (int i = 0; i < CC / 4; ++i) {
        float4 w4 = wr[i], c4 = cr[i], l4 = lr[i], u4 = ur[i];
        sc = fmaf(c4.x, w4.x, sc); sc = fmaf(c4.y, w4.y, sc);
        sc = fmaf(c4.z, w4.z, sc); sc = fmaf(c4.w, w4.w, sc);
        sm = fmaf((l4.x + u4.x) * 0.5f, w4.x, sm);
        sm = fmaf((l4.y + u4.y) * 0.5f, w4.y, sm);
        sm = fmaf((l4.z + u4.z) * 0.5f, w4.z, sm);
        sm = fmaf((l4.w + u4.w) * 0.5f, w4.w, sm);
        sr = fmaf((u4.x - l4.x) * 0.5f, fabsf(w4.x), sr);
        sr = fmaf((u4.y - l4.y) * 0.5f, fabsf(w4.y), sr);
        sr = fmaf((u4.z - l4.z) * 0.5f, fabsf(w4.z), sr);
        sr = fmaf((u4.w - l4.w) * 0.5f, fabsf(w4.w), sr);
    }
    size_t N = (size_t)B * Out;
    size_t base = (size_t)b * Out + o;
    float* p = P + (size_t)chunk * 3 * N;
    p[base] = sc; p[N + base] = sm; p[2 * N + base] = sr;
}

__global__ void fc_combine(const float* __restrict__ P, float* __restrict__ OUT,
                           size_t N, int NCH)
{
    size_t idx = (size_t)blockIdx.x * blockDim.x + threadIdx.x;
    if (idx >= N) return;
    float sc = 0.f, sm = 0.f, sr = 0.f;
    for (int ch = 0; ch < NCH; ++ch) {
        const float* p = P + (size_t)ch * 3 * N;
        sc += p[idx]; sm += p[N + idx]; sr += p[2 * N + idx];
    }
    OUT[idx]         = fmaxf(sc, 0.f);
    OUT[N + idx]     = fmaxf(sm - sr, 0.f);
    OUT[2 * N + idx] = fmaxf(sm + sr, 0.f);
}

__global__ void bound_linear_kernel(
    const float* __restrict__ IC, const float* __restrict__ IL, const float* __restrict__ IU,
    const float* __restrict__ W, const float* __restrict__ bias,
    float* __restrict__ OC, float* __restrict__ OL, float* __restrict__ OU,
    int B, int In, int Out)
{
    int idx = blockIdx.x * blockDim.x + threadIdx.x;
    if (idx >= B * Out) return;
    int o = idx % Out, b = idx / Out;
    const float* wr = W  + (size_t)o * In;
    const float* cr = IC + (size_t)b * In;
    const float* lr = IL + (size_t)b * In;
    const float* ur = IU + (size_t)b * In;
    float sc = 0.f, sm = 0.f, sr = 0.f;
    for (int i = 0; i < In; ++i) {
        float w = wr[i];
        sc = fmaf(cr[i], w, sc);
        sm = fmaf((lr[i] + ur[i]) * 0.5f, w, sm);
        sr = fmaf((ur[i] - lr[i]) * 0.5f, fabsf(w), sr);
    }
    float bb = bias[o]; sc += bb; sm += bb;
    OC[idx] = -sc; OL[idx] = -(sm - sr); OU[idx] = -(sm + sr);
}

extern "C" void kernel_launch(void* const* d_in, const int* in_sizes, int n_in,
                              void* d_out, int out_size, void* d_ws, size_t ws_size,
                              hipStream_t stream)
{
    const float* x   = (const float*)d_in[0];
    const float* lo  = (const float*)d_in[1];
    const float* hi  = (const float*)d_in[2];
    const float* w1  = (const float*)d_in[3];
    const float* w2  = (const float*)d_in[4];
    const float* w3  = (const float*)d_in[5];
    const float* w4  = (const float*)d_in[6];
    const float* w5  = (const float*)d_in[7];
    const float* fw1 = (const float*)d_in[8];
    const float* fw2 = (const float*)d_in[9];
    const float* fw3 = (const float*)d_in[10];
    const float* fb3 = (const float*)d_in[11];
    float* out = (float*)d_out;
    float* ws  = (float*)d_ws;

    const size_t n_c1 = 16u * 96 * 15 * 15;
    const size_t n_p1 = 16u * 96 * 7 * 7;
    const size_t n_c2 = 16u * 256 * 7 * 7;
    const size_t n_p2 = 16u * 256 * 3 * 3;
    const size_t n_c3 = 16u * 384 * 3 * 3;
    const size_t n_c4 = n_c3;
    const size_t n_c5 = 16u * 256 * 3 * 3;
    const size_t n_f1 = 16u * 1024;
    const size_t n_f2 = 16u * 512;

    float* A  = ws;
    float* Bp = A  + 3 * n_c1;
    float* Cc = Bp + 3 * n_p1;
    float* D  = Cc + 3 * n_c2;
    float* E  = D  + 3 * n_p2;
    float* F  = E  + 3 * n_c3;
    float* G  = F  + 3 * n_c4;
    float* H  = G  + 3 * n_c5;
    float* I  = H  + 3 * n_f1;
    float* SP = I  + 3 * n_f2;

    const int BS = 256;
    auto grid = [](size_t tot) { return dim3((unsigned)((tot + 255) / 256)); };

    // conv1: [16,3,32,32] k7 s2 p2 -> [16,96,15,15]; 1 chunk, ROOT
    conv_a<7, 2, 2, 3, 32, 32, 15, 15, true><<<384, BS, 0, stream>>>(
        x, lo, hi, w1, A, 16, 3, 96, 24);
    // pool1
    maxpool_kernel<<<grid(3 * n_p1), BS, 0, stream>>>(
        A, Bp, 16 * 96, 15, 15, 7, 7, (int)n_c1, (int)n_p1);
    // conv2: [16,96,7,7] k5 s1 p2 -> [16,256,7,7]; 2 chunks of 48
    conv_a<5, 1, 2, 48, 7, 7, 7, 7, false><<<2048, BS, 0, stream>>>(
        Bp, Bp + n_p1, Bp + 2 * n_p1, w2, SP, 16, 96, 256, 64);
    conv_combine<<<grid(3 * n_c2), BS, 0, stream>>>(SP, Cc, n_c2, 2);
    // pool2
    maxpool_kernel<<<grid(3 * n_p2), BS, 0, stream>>>(
        Cc, D, 16 * 256, 7, 7, 3, 3, (int)n_c2, (int)n_p2);
    // conv3: [16,256,3,3] -> [16,384,3,3]; 4 chunks of 64, OB=14
    conv_b<64><<<4 * 16 * 14, BS, 0, stream>>>(
        D, D + n_p2, D + 2 * n_p2, w3, SP, 16, 256, 384, 14);
    conv_combine<<<grid(3 * n_c3), BS, 0, stream>>>(SP, E, n_c3, 4);
    // conv4: [16,384,3,3] -> [16,384,3,3]; 4 chunks of 96, OB=14
    conv_b<96><<<4 * 16 * 14, BS, 0, stream>>>(
        E, E + n_c3, E + 2 * n_c3, w4, SP, 16, 384, 384, 14);
    conv_combine<<<grid(3 * n_c4), BS, 0, stream>>>(SP, F, n_c4, 4);
    // conv5: [16,384,3,3] -> [16,256,3,3]; 4 chunks of 96, OB=10
    conv_b<96><<<4 * 16 * 10, BS, 0, stream>>>(
        F, F + n_c4, F + 2 * n_c4, w5, SP, 16, 384, 256, 10);
    conv_combine<<<grid(3 * n_c5), BS, 0, stream>>>(SP, G, n_c5, 4);
    // fc1: 2304 -> 1024, relu; split 8x288
    fc_partial<<<grid(8u * 16 * 1024), BS, 0, stream>>>(
        G, G + n_c5, G + 2 * n_c5, fw1, SP, 16, 2304, 1024, 288, 8);
    fc_combine<<<grid(n_f1), BS, 0, stream>>>(SP, H, n_f1, 8);
    // fc2: 1024 -> 512, relu; split 8x128
    fc_partial<<<grid(8u * 16 * 512), BS, 0, stream>>>(
        H, H + n_f1, H + 2 * n_f1, fw2, SP, 16, 1024, 512, 128, 8);
    fc_combine<<<grid(n_f2), BS, 0, stream>>>(SP, I, n_f2, 8);
    // fc3: 512 -> 10, +bias, negate+swap: out = [-c | -u | -l]
    bound_linear_kernel<<<grid(160), BS, 0, stream>>>(
        I, I + n_f2, I + 2 * n_f2, fw3, fb3,
        out, out + 320, out + 160, 16, 512, 10);
}

// Round 4
// 691.105 us; speedup vs baseline: 5.9752x; 1.1075x over previous
//
#include <hip/hip_runtime.h>
#include <math.h>

// ---------------------------------------------------------------------------
// NormDist (Lp, p=8) IBP AlexNet. Round 4: lane=output-channel layout for
// conv2..5 -- LDS x-reads are wave-uniform broadcasts (conflict-free) and each
// x is reused across all output positions in registers; weights are per-lane
// global loads (L2-resident). Channel-split additive d^8 partials + combine.
// lp8(d) = (sum d^8)^(1/8); relu after conv = no-op (norms >= 0).
// ---------------------------------------------------------------------------

__device__ __forceinline__ float rt8(float s) { return sqrtf(sqrtf(sqrtf(s))); }

__device__ __forceinline__ void tap16(float w, float pc, float pl, float pu,
                                      float& aC, float& aL, float& aH)
{
    float a = pc - w; float a2 = a * a, a4 = a2 * a2; aC = fmaf(a4, a4, aC);
    float x = pl - w, y = pu - w;
    float dl = fmaxf(fmaxf(x, -y), 0.f);
    float e2 = dl * dl, e4 = e2 * e2; aL = fmaf(e4, e4, aL);
    float h2 = fmaxf(x * x, y * y);
    float h4 = h2 * h2; aH = fmaf(h4, h4, aH);
}

// conv1 only (structure from round 3: wave = one o, lanes = positions).
template<int K, int S, int PAD, int CC, int HIN, int WIN, int HO, int WO, bool ROOT>
__launch_bounds__(256)
__global__ void conv_a(const float* __restrict__ IC, const float* __restrict__ IL,
                       const float* __restrict__ IU, const float* __restrict__ W,
                       float* __restrict__ OUT, int B, int Cin, int O, int OG)
{
    constexpr int PH = (HO - 1) * S + K;
    constexpr int PW = (WO - 1) * S + K;
    constexpr int PP = PH * PW;
    constexpr int HW = HIN * WIN;
    constexpr int NP = HO * WO;
    constexpr int ROUNDS = (NP + 63) / 64;
    __shared__ float lds[CC * 3 * PP];

    int og = blockIdx.x % OG;
    int b  = (blockIdx.x / OG) % B;
    int chunk = blockIdx.x / (OG * B);
    int c0 = chunk * CC;
    int tid = threadIdx.x;

    for (int i = tid; i < CC * 3 * PP; i += 256) lds[i] = 0.f;
    __syncthreads();
    for (int tsel = 0; tsel < 3; ++tsel) {
        const float* src = (tsel == 0 ? IC : (tsel == 1 ? IL : IU))
                         + ((size_t)b * Cin + c0) * HW;
        for (int e = tid; e < CC * HW; e += 256) {
            int c = e / HW, p = e % HW;
            int pr = p / WIN, pw_ = p % WIN;
            lds[c * 3 * PP + tsel * PP + (pr + PAD) * PW + (pw_ + PAD)] = src[e];
        }
    }
    __syncthreads();

    int wave = tid >> 6, lane = tid & 63;
    int o = __builtin_amdgcn_readfirstlane(og * 4 + wave);
    const float* wp = W + ((size_t)o * Cin + c0) * (K * K);

    for (int r = 0; r < ROUNDS; ++r) {
        int pos = r * 64 + lane;
        bool act = pos < NP;
        int pp = act ? pos : 0;
        int oh = pp / WO, ow = pp % WO;
        const float* sl = lds + (oh * S) * PW + ow * S;
        const float* wc = wp;
        float aC = 0.f, aL = 0.f, aH = 0.f;
        for (int c = 0; c < CC; ++c) {
            #pragma unroll
            for (int kh = 0; kh < K; ++kh)
                #pragma unroll
                for (int kw = 0; kw < K; ++kw) {
                    float w = wc[kh * K + kw];
                    tap16(w, sl[kh * PW + kw], sl[PP + kh * PW + kw],
                          sl[2 * PP + kh * PW + kw], aC, aL, aH);
                }
            sl += 3 * PP; wc += K * K;
        }
        if (act) {
            size_t N = (size_t)B * O * NP;
            size_t oidx = ((size_t)b * O + o) * NP + pos;
            if (ROOT) {
                OUT[oidx] = rt8(aC); OUT[N + oidx] = rt8(aL); OUT[2 * N + oidx] = rt8(aH);
            } else {
                float* P = OUT + (size_t)chunk * 3 * N;
                P[oidx] = aC; P[N + oidx] = aL; P[2 * N + oidx] = aH;
            }
        }
    }
}

// conv2: lane = o (64 per wave, 2 waves/block), block owns one output row oh.
// LDS slab [CC][3][5 rows][11 cols] padded; all x-reads are broadcasts.
// IN: 3 tensors at stride nin. P: chunk-partial d^8 sums.
template<int CC>
__launch_bounds__(128)
__global__ void conv2_kernel(const float* __restrict__ IN, const float* __restrict__ W,
                             float* __restrict__ P, int nin)
{
    constexpr int B = 16, Cin = 96, O = 256;
    __shared__ float slab[CC * 165];  // c*165 + tsel*55 + r*11 + col
    int x = blockIdx.x;
    int pair = x % 2;
    int oh   = (x / 2) % 7;
    int b    = (x / 14) % B;
    int chunk = x / (14 * B);
    int c0 = chunk * CC;
    int tid = threadIdx.x;

    for (int i = tid; i < CC * 165; i += 128) {
        int c = i / 165; int rem = i % 165;
        int tsel = rem / 55; int rr = rem % 55;
        int r = rr / 11, col = rr % 11;
        int ih = oh + r - 2, iw = col - 2;
        float v = 0.f;
        if ((unsigned)ih < 7u && (unsigned)iw < 7u)
            v = IN[(size_t)tsel * nin + ((size_t)b * Cin + c0 + c) * 49 + ih * 7 + iw];
        slab[i] = v;
    }
    __syncthreads();

    int wave = tid >> 6, lane = tid & 63;
    int o = (pair * 2 + wave) * 64 + lane;

    float aC[7], aL[7], aH[7];
    #pragma unroll
    for (int u = 0; u < 7; ++u) { aC[u] = 0.f; aL[u] = 0.f; aH[u] = 0.f; }

    for (int c = 0; c < CC; ++c) {
        const float* wp = W + ((size_t)o * Cin + c0 + c) * 25;
        float w[25];
        #pragma unroll
        for (int t = 0; t < 25; ++t) w[t] = wp[t];
        const float* sb = slab + c * 165;
        #pragma unroll
        for (int r = 0; r < 5; ++r) {
            #pragma unroll
            for (int i = 0; i < 11; ++i) {
                float xc = sb[r * 11 + i];
                float xl = sb[55 + r * 11 + i];
                float xu = sb[110 + r * 11 + i];
                #pragma unroll
                for (int ow = 0; ow < 7; ++ow) {
                    int kw = i - ow;
                    if (kw >= 0 && kw < 5)
                        tap16(w[r * 5 + kw], xc, xl, xu, aC[ow], aL[ow], aH[ow]);
                }
            }
        }
    }

    size_t N = (size_t)B * O * 49;
    size_t base = (((size_t)b * O + o) * 7 + oh) * 7;
    float* Pc = P + (size_t)chunk * 3 * N;
    #pragma unroll
    for (int u = 0; u < 7; ++u) {
        Pc[base + u] = aC[u]; Pc[N + base + u] = aL[u]; Pc[2 * N + base + u] = aH[u];
    }
}

// conv3/4/5 (3x3 maps, k3 p1): lane = o, 2 waves/block, 9 outputs per lane.
// LDS slab [CC][3][25] (padded 5x5); broadcast x-reads, register-resident acc.
template<int CC>
__launch_bounds__(128)
__global__ void conv3x3_kernel(const float* __restrict__ IN, const float* __restrict__ W,
                               float* __restrict__ P, int nin, int B, int Cin, int O,
                               int PAIRS)
{
    __shared__ float slab[CC * 75];  // c*75 + tsel*25 + iy*5 + ix
    int x = blockIdx.x;
    int pair = x % PAIRS;
    int b    = (x / PAIRS) % B;
    int chunk = x / (PAIRS * B);
    int c0 = chunk * CC;
    int tid = threadIdx.x;

    for (int i = tid; i < CC * 75; i += 128) {
        int c = i / 75; int rem = i % 75;
        int tsel = rem / 25; int rr = rem % 25;
        int iy = rr / 5, ix = rr % 5;
        int ih = iy - 1, iw = ix - 1;
        float v = 0.f;
        if ((unsigned)ih < 3u && (unsigned)iw < 3u)
            v = IN[(size_t)tsel * nin + ((size_t)b * Cin + c0 + c) * 9 + ih * 3 + iw];
        slab[i] = v;
    }
    __syncthreads();

    int wave = tid >> 6, lane = tid & 63;
    int o = (pair * 2 + wave) * 64 + lane;

    float aC[9], aL[9], aH[9];
    #pragma unroll
    for (int u = 0; u < 9; ++u) { aC[u] = 0.f; aL[u] = 0.f; aH[u] = 0.f; }

    for (int c = 0; c < CC; ++c) {
        const float* wp = W + ((size_t)o * Cin + c0 + c) * 9;
        float w[9];
        #pragma unroll
        for (int t = 0; t < 9; ++t) w[t] = wp[t];
        const float* sb = slab + c * 75;
        #pragma unroll
        for (int iy = 0; iy < 5; ++iy) {
            #pragma unroll
            for (int ix = 0; ix < 5; ++ix) {
                float xc = sb[iy * 5 + ix];
                float xl = sb[25 + iy * 5 + ix];
                float xu = sb[50 + iy * 5 + ix];
                #pragma unroll
                for (int py = 0; py < 3; ++py) {
                    int ky = iy - py;
                    if (ky < 0 || ky > 2) continue;
                    #pragma unroll
                    for (int px = 0; px < 3; ++px) {
                        int kx = ix - px;
                        if (kx < 0 || kx > 2) continue;
                        tap16(w[ky * 3 + kx], xc, xl, xu,
                              aC[py * 3 + px], aL[py * 3 + px], aH[py * 3 + px]);
                    }
                }
            }
        }
    }

    size_t N = (size_t)B * O * 9;
    size_t base = ((size_t)b * O + o) * 9;
    float* Pc = P + (size_t)chunk * 3 * N;
    #pragma unroll
    for (int u = 0; u < 9; ++u) {
        Pc[base + u] = aC[u]; Pc[N + base + u] = aL[u]; Pc[2 * N + base + u] = aH[u];
    }
}

// Sum NCH partial d^8 blocks and apply ^(1/8).
__global__ void conv_combine(const float* __restrict__ P, float* __restrict__ OUT,
                             size_t N, int NCH)
{
    size_t idx = (size_t)blockIdx.x * blockDim.x + threadIdx.x;
    if (idx >= 3 * N) return;
    float s = 0.f;
    for (int ch = 0; ch < NCH; ++ch) s += P[(size_t)ch * 3 * N + idx];
    OUT[idx] = rt8(s);
}

__global__ void maxpool_kernel(const float* __restrict__ in, float* __restrict__ out,
                               int BC, int Hin, int Win, int Ho, int Wo,
                               int n_in, int n_out)
{
    int idx = blockIdx.x * blockDim.x + threadIdx.x;
    int per = BC * Ho * Wo;
    if (idx >= 3 * per) return;
    int tsel = idx / per; int r = idx - tsel * per;
    int ow = r % Wo; int t2 = r / Wo;
    int oh = t2 % Ho; int bc = t2 / Ho;
    const float* ip = in + (size_t)tsel * n_in + (size_t)bc * Hin * Win;
    int ih0 = oh * 2, iw0 = ow * 2;
    float m = -INFINITY;
    #pragma unroll
    for (int i = 0; i < 3; ++i)
        #pragma unroll
        for (int j = 0; j < 3; ++j)
            m = fmaxf(m, ip[(ih0 + i) * Win + (iw0 + j)]);
    out[(size_t)tsel * n_out + r] = m;
}

__global__ void fc_partial(
    const float* __restrict__ IC, const float* __restrict__ IL, const float* __restrict__ IU,
    const float* __restrict__ W, float* __restrict__ P,
    int B, int In, int Out, int CC, int NCH)
{
    int idx = blockIdx.x * blockDim.x + threadIdx.x;
    if (idx >= NCH * B * Out) return;
    int o = idx % Out; int t = idx / Out;
    int b = t % B; int chunk = t / B;
    int i0 = chunk * CC;
    const float4* wr = (const float4*)(W  + (size_t)o * In + i0);
    const float4* cr = (const float4*)(IC + (size_t)b * In + i0);
    const float4* lr = (const float4*)(IL + (size_t)b * In + i0);
    const float4* ur = (const float4*)(IU + (size_t)b * In + i0);
    float sc = 0.f, sm = 0.f, sr = 0.f;
    for (int i = 0; i < CC / 4; ++i) {
        float4 w4 = wr[i], c4 = cr[i], l4 = lr[i], u4 = ur[i];
        sc = fmaf(c4.x, w4.x, sc); sc = fmaf(c4.y, w4.y, sc);
        sc = fmaf(c4.z, w4.z, sc); sc = fmaf(c4.w, w4.w, sc);
        sm = fmaf((l4.x + u4.x) * 0.5f, w4.x, sm);
        sm = fmaf((l4.y + u4.y) * 0.5f, w4.y, sm);
        sm = fmaf((l4.z + u4.z) * 0.5f, w4.z, sm);
        sm = fmaf((l4.w + u4.w) * 0.5f, w4.w, sm);
        sr = fmaf((u4.x - l4.x) * 0.5f, fabsf(w4.x), sr);
        sr = fmaf((u4.y - l4.y) * 0.5f, fabsf(w4.y), sr);
        sr = fmaf((u4.z - l4.z) * 0.5f, fabsf(w4.z), sr);
        sr = fmaf((u4.w - l4.w) * 0.5f, fabsf(w4.w), sr);
    }
    size_t N = (size_t)B * Out;
    size_t base = (size_t)b * Out + o;
    float* p = P + (size_t)chunk * 3 * N;
    p[base] = sc; p[N + base] = sm; p[2 * N + base] = sr;
}

__global__ void fc_combine(const float* __restrict__ P, float* __restrict__ OUT,
                           size_t N, int NCH)
{
    size_t idx = (size_t)blockIdx.x * blockDim.x + threadIdx.x;
    if (idx >= N) return;
    float sc = 0.f, sm = 0.f, sr = 0.f;
    for (int ch = 0; ch < NCH; ++ch) {
        const float* p = P + (size_t)ch * 3 * N;
        sc += p[idx]; sm += p[N + idx]; sr += p[2 * N + idx];
    }
    OUT[idx]         = fmaxf(sc, 0.f);
    OUT[N + idx]     = fmaxf(sm - sr, 0.f);
    OUT[2 * N + idx] = fmaxf(sm + sr, 0.f);
}

__global__ void bound_linear_kernel(
    const float* __restrict__ IC, const float* __restrict__ IL, const float* __restrict__ IU,
    const float* __restrict__ W, const float* __restrict__ bias,
    float* __restrict__ OC, float* __restrict__ OL, float* __restrict__ OU,
    int B, int In, int Out)
{
    int idx = blockIdx.x * blockDim.x + threadIdx.x;
    if (idx >= B * Out) return;
    int o = idx % Out, b = idx / Out;
    const float* wr = W  + (size_t)o * In;
    const float* cr = IC + (size_t)b * In;
    const float* lr = IL + (size_t)b * In;
    const float* ur = IU + (size_t)b * In;
    float sc = 0.f, sm = 0.f, sr = 0.f;
    for (int i = 0; i < In; ++i) {
        float w = wr[i];
        sc = fmaf(cr[i], w, sc);
        sm = fmaf((lr[i] + ur[i]) * 0.5f, w, sm);
        sr = fmaf((ur[i] - lr[i]) * 0.5f, fabsf(w), sr);
    }
    float bb = bias[o]; sc += bb; sm += bb;
    OC[idx] = -sc; OL[idx] = -(sm - sr); OU[idx] = -(sm + sr);
}

extern "C" void kernel_launch(void* const* d_in, const int* in_sizes, int n_in,
                              void* d_out, int out_size, void* d_ws, size_t ws_size,
                              hipStream_t stream)
{
    const float* x   = (const float*)d_in[0];
    const float* lo  = (const float*)d_in[1];
    const float* hi  = (const float*)d_in[2];
    const float* w1  = (const float*)d_in[3];
    const float* w2  = (const float*)d_in[4];
    const float* w3  = (const float*)d_in[5];
    const float* w4  = (const float*)d_in[6];
    const float* w5  = (const float*)d_in[7];
    const float* fw1 = (const float*)d_in[8];
    const float* fw2 = (const float*)d_in[9];
    const float* fw3 = (const float*)d_in[10];
    const float* fb3 = (const float*)d_in[11];
    float* out = (float*)d_out;
    float* ws  = (float*)d_ws;

    const size_t n_c1 = 16u * 96 * 15 * 15;
    const size_t n_p1 = 16u * 96 * 7 * 7;
    const size_t n_c2 = 16u * 256 * 7 * 7;
    const size_t n_p2 = 16u * 256 * 3 * 3;
    const size_t n_c3 = 16u * 384 * 3 * 3;
    const size_t n_c4 = n_c3;
    const size_t n_c5 = 16u * 256 * 3 * 3;
    const size_t n_f1 = 16u * 1024;
    const size_t n_f2 = 16u * 512;

    float* A  = ws;
    float* Bp = A  + 3 * n_c1;
    float* Cc = Bp + 3 * n_p1;
    float* D  = Cc + 3 * n_c2;
    float* E  = D  + 3 * n_p2;
    float* F  = E  + 3 * n_c3;
    float* G  = F  + 3 * n_c4;
    float* H  = G  + 3 * n_c5;
    float* I  = H  + 3 * n_f1;
    float* SP = I  + 3 * n_f2;   // partial scratch; max use = 32*3*n_c4 floats

    const int BS = 256;
    auto grid = [](size_t tot) { return dim3((unsigned)((tot + 255) / 256)); };

    // conv1: [16,3,32,32] k7 s2 p2 -> [16,96,15,15]
    conv_a<7, 2, 2, 3, 32, 32, 15, 15, true><<<384, BS, 0, stream>>>(
        x, lo, hi, w1, A, 16, 3, 96, 24);
    // pool1
    maxpool_kernel<<<grid(3 * n_p1), BS, 0, stream>>>(
        A, Bp, 16 * 96, 15, 15, 7, 7, (int)n_c1, (int)n_p1);
    // conv2: lane=o; NCH=6 chunks of CC=16; grid = 6*16*7*2
    conv2_kernel<16><<<6 * 16 * 7 * 2, 128, 0, stream>>>(Bp, w2, SP, (int)n_p1);
    conv_combine<<<grid(3 * n_c2), BS, 0, stream>>>(SP, Cc, n_c2, 6);
    // pool2
    maxpool_kernel<<<grid(3 * n_p2), BS, 0, stream>>>(
        Cc, D, 16 * 256, 7, 7, 3, 3, (int)n_c2, (int)n_p2);
    // conv3: Cin=256, O=384 (PAIRS=3); CC=8, NCH=32; grid = 32*16*3
    conv3x3_kernel<8><<<32 * 16 * 3, 128, 0, stream>>>(
        D, w3, SP, (int)n_p2, 16, 256, 384, 3);
    conv_combine<<<grid(3 * n_c3), BS, 0, stream>>>(SP, E, n_c3, 32);
    // conv4: Cin=384, O=384 (PAIRS=3); CC=12, NCH=32; grid = 32*16*3
    conv3x3_kernel<12><<<32 * 16 * 3, 128, 0, stream>>>(
        E, w4, SP, (int)n_c3, 16, 384, 384, 3);
    conv_combine<<<grid(3 * n_c4), BS, 0, stream>>>(SP, F, n_c4, 32);
    // conv5: Cin=384, O=256 (PAIRS=2); CC=12, NCH=32; grid = 32*16*2
    conv3x3_kernel<12><<<32 * 16 * 2, 128, 0, stream>>>(
        F, w5, SP, (int)n_c4, 16, 384, 256, 2);
    conv_combine<<<grid(3 * n_c5), BS, 0, stream>>>(SP, G, n_c5, 32);
    // fc1: 2304 -> 1024, relu; split 8x288
    fc_partial<<<grid(8u * 16 * 1024), BS, 0, stream>>>(
        G, G + n_c5, G + 2 * n_c5, fw1, SP, 16, 2304, 1024, 288, 8);
    fc_combine<<<grid(n_f1), BS, 0, stream>>>(SP, H, n_f1, 8);
    // fc2: 1024 -> 512, relu; split 8x128
    fc_partial<<<grid(8u * 16 * 512), BS, 0, stream>>>(
        H, H + n_f1, H + 2 * n_f1, fw2, SP, 16, 1024, 512, 128, 8);
    fc_combine<<<grid(n_f2), BS, 0, stream>>>(SP, I, n_f2, 8);
    // fc3: 512 -> 10, +bias, negate+swap: out = [-c | -u | -l]
    bound_linear_kernel<<<grid(160), BS, 0, stream>>>(
        I, I + n_f2, I + 2 * n_f2, fw3, fb3,
        out, out + 320, out + 160, 16, 512, 10);
}